// Round 10
// baseline (34.255 us; speedup 1.0000x reference)
//
#include <hip/hip_runtime.h>

// NonLocalMean: x (4,64,128,128) fp32, K=7 (rad 3), HEADS=4 -> mid=16.
// w_p = exp(2<n_p,c> - ||n_p||^2 - ||c||^2) = exp(-||n_p-c||^2) <= 1 (softmax
// max is 0 at the center) -> plain sum, no online rescale.
// out = x + (sum_p w_p n_p)/(sum_p w_p); zero-padded OOB patches are zero
// vectors contributing exp(-||c||^2) to the denominator.
//
// R10 = R2 math + R1 occupancy recipe, calibrated on R1's counters
// (VALUBusy*dur => emitted VALU ~2x hand count; R1 was VALU-bound at 66%).
// fp32 is the minimum-total-VALU config: no bf16 unpack, one exp, no
// cross-lane reduce. The one R2 flaw (unroll 2 -> two visits + hoisted
// loads live -> >128 VGPR -> 2 waves/SIMD) is fixed: wx fully ROLLED, one
// visit live (~66 regs hand-counted -> expect 80-96 VGPR -> 4-5 waves/SIMD
// natural; LDS 38.7KB -> 4 blocks/CU). Record = 20 dwords (16 ch + nn +
// 3 pad): 20/4=5 odd -> b128 chunk bank-groups (5p+k)%8 balanced, nn at
// +16 within the same record (one base reg, imm offsets only).

#define TW    16
#define RAD   3
#define HWD   22                 // 16 + 6
#define NPIX  (HWD * HWD)        // 484
#define MID   16
#define PSTR  20                 // dwords per record (80 B)
#define IMG   128
#define PLANE (IMG * IMG)

__global__ __launch_bounds__(256)
void nlm_kernel(const float* __restrict__ x, float* __restrict__ out) {
    const int g   = blockIdx.z & 3;
    const int b   = blockIdx.z >> 2;
    const int tx0 = blockIdx.x * TW;
    const int ty0 = blockIdx.y * TW;

    __shared__ __align__(16) float rec[NPIX * PSTR];   // 38,720 B

    const int tid = threadIdx.x;
    const int lx  = tid & 15;
    const int ly  = tid >> 4;
    const float* xb = x + (size_t)(b * 64 + g * MID) * PLANE;

    // ---- stage halo: fp32 channels + ||n||^2 in slot 16 (fused, 1 barrier) ----
    #pragma unroll 1
    for (int i = tid; i < NPIX; i += 256) {
        const int yy = i / HWD;
        const int xx = i - yy * HWD;
        const int gy = ty0 + yy - RAD;
        const int gx = tx0 + xx - RAD;
        const bool in = ((unsigned)gy < (unsigned)IMG) & ((unsigned)gx < (unsigned)IMG);
        const float* p = xb + gy * IMG + gx;
        float* rp = &rec[i * PSTR];
        float s0 = 0.f, s1 = 0.f;
        #pragma unroll
        for (int c = 0; c < MID; c += 2) {
            const float v0 = in ? p[c * PLANE] : 0.f;
            const float v1 = in ? p[(c + 1) * PLANE] : 0.f;
            rp[c]     = v0;
            rp[c + 1] = v1;
            s0 = fmaf(v0, v0, s0);
            s1 = fmaf(v1, v1, s1);
        }
        rp[MID] = s0 + s1;
    }
    __syncthreads();

    // ---- exact center from registers via LDS (same values, fp32) ----
    const float* base = &rec[(ly * HWD + lx) * PSTR];
    float ctr[MID];
    {
        const float* cp = base + (3 * HWD + 3) * PSTR;
        #pragma unroll
        for (int k = 0; k < 4; ++k) {
            const float4 v = *reinterpret_cast<const float4*>(cp + 4 * k);
            ctr[4 * k + 0] = v.x; ctr[4 * k + 1] = v.y;
            ctr[4 * k + 2] = v.z; ctr[4 * k + 3] = v.w;
        }
    }
    const float cc = base[(3 * HWD + 3) * PSTR + MID];

    float acc[MID];
    #pragma unroll
    for (int c = 0; c < MID; ++c) acc[c] = 0.f;
    float s = 0.f;

    // ---- 49 visits; BOTH loops rolled: exactly one visit live ----
    #pragma unroll 1
    for (int wy = 0; wy < 7; ++wy) {
        const float* rp = base + wy * (HWD * PSTR);
        #pragma unroll 1
        for (int wx = 0; wx < 7; ++wx) {
            const float4 v0 = *reinterpret_cast<const float4*>(rp + 0);
            const float4 v1 = *reinterpret_cast<const float4*>(rp + 4);
            const float4 v2 = *reinterpret_cast<const float4*>(rp + 8);
            const float4 v3 = *reinterpret_cast<const float4*>(rp + 12);
            const float nn = rp[MID];
            float nb[MID];
            nb[0]  = v0.x; nb[1]  = v0.y; nb[2]  = v0.z; nb[3]  = v0.w;
            nb[4]  = v1.x; nb[5]  = v1.y; nb[6]  = v1.z; nb[7]  = v1.w;
            nb[8]  = v2.x; nb[9]  = v2.y; nb[10] = v2.z; nb[11] = v2.w;
            nb[12] = v3.x; nb[13] = v3.y; nb[14] = v3.z; nb[15] = v3.w;

            float d0 = 0.f, d1 = 0.f, d2 = 0.f, d3 = 0.f;
            #pragma unroll
            for (int c = 0; c < MID; c += 4) {
                d0 = fmaf(nb[c + 0], ctr[c + 0], d0);
                d1 = fmaf(nb[c + 1], ctr[c + 1], d1);
                d2 = fmaf(nb[c + 2], ctr[c + 2], d2);
                d3 = fmaf(nb[c + 3], ctr[c + 3], d3);
            }
            const float dot = (d0 + d1) + (d2 + d3);
            const float w = __expf(fmaf(2.f, dot, -(nn + cc)));
            s += w;
            #pragma unroll
            for (int c = 0; c < MID; ++c) acc[c] = fmaf(w, nb[c], acc[c]);
            rp += PSTR;
        }
    }

    const float inv = 1.f / s;
    float* ob = out + (size_t)(b * 64 + g * MID) * PLANE
                    + (size_t)(ty0 + ly) * IMG + (tx0 + lx);
    #pragma unroll
    for (int c = 0; c < MID; ++c)
        ob[c * PLANE] = fmaf(acc[c], inv, ctr[c]);
}

extern "C" void kernel_launch(void* const* d_in, const int* in_sizes, int n_in,
                              void* d_out, int out_size, void* d_ws, size_t ws_size,
                              hipStream_t stream) {
    const float* x = (const float*)d_in[0];
    float* out = (float*)d_out;
    dim3 grid(IMG / TW, IMG / TW, 16);   // 8 x 8 x (B=4 * HEADS=4) = 1024 blocks
    nlm_kernel<<<grid, 256, 0, stream>>>(x, out);
}